// Round 7
// baseline (383.833 us; speedup 1.0000x reference)
//
#include <hip/hip_runtime.h>
#include <math.h>

// DetectionLoss: masked pairwise IoU + exact Hungarian + scalar loss.
//
// r7: DIAGNOSTIC round. Kernel is byte-identical to r6 (r5 solver).
// We launch it 11x back-to-back with disjoint workspace generations to
// measure the true per-launch kernel cost K from the dur delta:
//   dur_r7 = floor + 11*K + 10*gap   vs   dur_r6 = floor + K
// Each generation's flags live in its own ws slice (poisoned 0xAA != 1
// before every timed call, so every launch sees fresh flags). Every
// launch computes and writes the same correct out[0]; last write wins.

constexpr int BIMG = 8;
constexpr int NBOX = 200;
constexpr int NCLS = 5;
constexpr int NBLK = BIMG * NCLS;
constexpr float SCORE_THR = 0.001f;
constexpr int NREP = 11;            // diagnostic repeat count
constexpr int GEN_STRIDE = 256;     // f32 elements per generation slice

__device__ __forceinline__ int   rl_i(int x, int l)   { return __builtin_amdgcn_readlane(x, l); }
__device__ __forceinline__ float rl_f(float x, int l) { return __int_as_float(__builtin_amdgcn_readlane(__float_as_int(x), l)); }

#define MIN_DPP_STEP(CTRL)                                                   \
    {                                                                        \
        unsigned ok = (unsigned)__builtin_amdgcn_update_dpp(                 \
            (int)key, (int)key, (CTRL), 0xF, 0xF, false);                    \
        key = (ok < key) ? ok : key;                                         \
    }
#define SUM_DPP_STEP(CTRL)                                                   \
    {                                                                        \
        float o = __int_as_float(__builtin_amdgcn_update_dpp(                \
            __float_as_int(acc), __float_as_int(acc), (CTRL), 0xF, 0xF, false)); \
        acc += o;                                                            \
    }

__global__ void __launch_bounds__(64)
det_fused_kernel(const float* __restrict__ boxes1,
                 const float* __restrict__ boxes2,
                 float* __restrict__ sum_part,
                 int* __restrict__ m1_part, int* __restrict__ m2_part,
                 int* __restrict__ flags,
                 float* __restrict__ out)
{
    const int lane = threadIdx.x;
    const int blk  = blockIdx.x;
    const int b    = blk / NCLS;
    const int ci   = blk % NCLS;
    const int cls  = (ci == 0) ? 1 : (ci == 1) ? 2 : (ci == 2) ? 3 : (ci == 3) ? 5 : 7;
    const unsigned long long ltm = (1ull << lane) - 1ull;

    __shared__ float4 bs1[NBOX], bs2[NBOX];
    __shared__ float4 rcomp[64], ccomp[64];
    __shared__ float2 cmeta[64];
    __shared__ float uarr[NBOX + 1], varr[NBOX + 1], minvarr[NBOX + 1];
    __shared__ int   wayarr[NBOX + 1], parr[NBOX + 1], usedarr[NBOX + 1];

    const float* g1 = boxes1 + (size_t)b * NBOX * 6;
    const float* g2 = boxes2 + (size_t)b * NBOX * 6;

    // ---- phase 1: hoist ALL global loads, then ballot-compact per class
    float2 A[12], B[12];
    #pragma unroll
    for (int c = 0; c < 4; ++c) {
        int t = c * 64 + lane;
        if (t < NBOX) {
            const float2* p = (const float2*)(g1 + (size_t)t * 6);
            A[3*c] = p[0]; A[3*c+1] = p[1]; A[3*c+2] = p[2];
            const float2* q = (const float2*)(g2 + (size_t)t * 6);
            B[3*c] = q[0]; B[3*c+1] = q[1]; B[3*c+2] = q[2];
        } else {
            A[3*c] = A[3*c+1] = make_float2(0.f, 0.f); A[3*c+2] = make_float2(0.f, -1.f);
            B[3*c] = B[3*c+1] = make_float2(0.f, 0.f); B[3*c+2] = make_float2(0.f, -1.f);
        }
    }
    int m1 = 0, m2 = 0;
    #pragma unroll
    for (int c = 0; c < 4; ++c) {
        int t = c * 64 + lane;
        bool pr = (t < NBOX) && (A[3*c+2].x > SCORE_THR) && ((int)A[3*c+2].y == cls);
        unsigned long long mk = __ballot(pr);
        if (pr) bs1[m1 + (int)__popcll(mk & ltm)] =
            make_float4(A[3*c].x, A[3*c].y, A[3*c+1].x, A[3*c+1].y);
        m1 += (int)__popcll(mk);
        pr = (t < NBOX) && (B[3*c+2].x > SCORE_THR) && ((int)B[3*c+2].y == cls);
        mk = __ballot(pr);
        if (pr) bs2[m2 + (int)__popcll(mk & ltm)] =
            make_float4(B[3*c].x, B[3*c].y, B[3*c+1].x, B[3*c+1].y);
        m2 += (int)__popcll(mk);
    }
    __syncthreads();

    float blockContrib = 0.f;

    do {
        if (m1 == 0 || m2 == 0) break;
        const int nmax = (m1 > m2) ? m1 : m2;

        if (nmax > 64) {
            // =================== LDS fallback (n > 64) ====================
            const int n = nmax;
            for (int j = lane; j <= n; j += 64) { varr[j] = 0.f; parr[j] = 0; uarr[j] = 0.f; }
            __syncthreads();
            int j0 = 0;
            for (int i2 = 1; i2 <= n; ++i2) {
                if (lane == 0) parr[0] = i2;
                for (int j = lane; j <= n; j += 64) { minvarr[j] = INFINITY; usedarr[j] = 0; }
                j0 = 0;
                __syncthreads();
                for (int it = 0; it <= n + 1; ++it) {
                    if (lane == 0) usedarr[j0] = 1;
                    __syncthreads();
                    const int i0 = parr[j0];
                    const float u0 = uarr[i0];
                    const bool rowReal = (i0 <= m1);
                    float4 rbx = make_float4(0,0,0,0); float ra = 0.f;
                    if (rowReal) { rbx = bs1[i0-1]; ra = (rbx.z-rbx.x)*(rbx.w-rbx.y); }
                    for (int j = lane; j <= n; j += 64) {
                        if (j >= 1 && !usedarr[j]) {
                            float cost = 0.f;
                            if (rowReal && j <= m2) {
                                float4 cbx = bs2[j-1];
                                float iw = fmaxf(fminf(rbx.z, cbx.z) - fmaxf(rbx.x, cbx.x), 0.f);
                                float ih = fmaxf(fminf(rbx.w, cbx.w) - fmaxf(rbx.y, cbx.y), 0.f);
                                float inter = iw * ih;
                                float ca = (cbx.z-cbx.x)*(cbx.w-cbx.y);
                                cost = -(inter / (ra + ca - inter));
                            }
                            float curv = cost - u0 - varr[j];
                            if (curv < minvarr[j]) { minvarr[j] = curv; wayarr[j] = j0; }
                        }
                    }
                    __syncthreads();
                    float bv = INFINITY; int bu = 0, bj = n + 1;
                    for (int j = lane; j <= n; j += 64) {
                        float m = usedarr[j] ? INFINITY : minvarr[j];
                        int un = (parr[j] == 0) ? 1 : 0;
                        if (m < bv || (m == bv && (un > bu || (un == bu && j < bj))))
                            { bv = m; bu = un; bj = j; }
                    }
                    #pragma unroll
                    for (int off = 32; off; off >>= 1) {
                        float ov2 = __shfl_xor(bv, off);
                        int ou = __shfl_xor(bu, off);
                        int oj = __shfl_xor(bj, off);
                        if (ov2 < bv || (ov2 == bv && (ou > bu || (ou == bu && oj < bj))))
                            { bv = ov2; bu = ou; bj = oj; }
                    }
                    j0 = bj;
                    const float delta = bv;
                    for (int j = lane; j <= n; j += 64) {
                        if (usedarr[j]) { uarr[parr[j]] += delta; varr[j] -= delta; }
                        else            { minvarr[j] -= delta; }
                    }
                    __syncthreads();
                    if (parr[j0] == 0) break;
                }
                if (lane == 0) {
                    int jj = j0, gg = 0;
                    while (jj != 0 && gg++ <= n + 1) { int j1 = wayarr[jj]; parr[jj] = parr[j1]; jj = j1; }
                }
                __syncthreads();
            }
            float contrib = 0.f;
            for (int j = lane; j <= n; j += 64) {
                if (j >= 1 && j <= m2) {
                    int pi = parr[j];
                    if (pi >= 1 && pi <= m1) {
                        float4 rbx = bs1[pi-1], cbx = bs2[j-1];
                        float iw = fmaxf(fminf(rbx.z, cbx.z) - fmaxf(rbx.x, cbx.x), 0.f);
                        float ih = fmaxf(fminf(rbx.w, cbx.w) - fmaxf(rbx.y, cbx.y), 0.f);
                        float inter = iw * ih;
                        float ra = (rbx.z-rbx.x)*(rbx.w-rbx.y);
                        float ca = (cbx.z-cbx.x)*(cbx.w-cbx.y);
                        contrib += inter / (ra + ca - inter);
                    }
                }
            }
            #pragma unroll
            for (int off = 32; off; off >>= 1) contrib += __shfl_xor(contrib, off);
            blockContrib = contrib;
            break;
        }

        // ====================== register fast path ========================
        const bool sw = (m1 > m2);
        const float4* rS = sw ? bs2 : bs1;
        const float4* cS = sw ? bs1 : bs2;
        const int mr = sw ? m2 : m1;
        const int mc = sw ? m1 : m2;

        float4 cb = make_float4(0,0,0,0);
        if (lane < mc) cb = cS[lane];
        float cba = (cb.z - cb.x) * (cb.w - cb.y);

        // ---- merged NZ scan + column reduction (unrolled x4)
        unsigned long long rowmask = 0ull;
        float cmin = 0.f; int carg = -1;
        #define SCAN1(ii)                                                      \
        {                                                                      \
            float4 rbv = rS[(ii)];                                             \
            float iw = fminf(rbv.z, cb.z) - fmaxf(rbv.x, cb.x);                \
            float ih = fminf(rbv.w, cb.w) - fmaxf(rbv.y, cb.y);                \
            bool ov = (lane < mc) && (iw > 0.f) && (ih > 0.f);                 \
            unsigned long long bal = __ballot(ov);                             \
            if (bal) rowmask |= (1ull << (ii));                                \
            if (ov) {                                                          \
                float inter = iw * ih;                                         \
                float ra2 = (rbv.z - rbv.x) * (rbv.w - rbv.y);                 \
                float cst = -(inter / (ra2 + cba - inter));                    \
                if (cst < cmin) { cmin = cst; carg = (ii); }                   \
            }                                                                  \
        }
        int i = 0;
        for (; i + 4 <= mr; i += 4) { SCAN1(i) SCAN1(i+1) SCAN1(i+2) SCAN1(i+3) }
        for (; i < mr; ++i) { SCAN1(i) }
        #undef SCAN1

        const int mrP = (int)__popcll(rowmask);
        if (mrP == 0) break;
        const unsigned long long colmask = __ballot(carg >= 0);
        const int mcP = (int)__popcll(colmask);
        const int nC = (mrP > mcP) ? mrP : mcP;

        int cargc = (carg >= 0) ? (int)__popcll(rowmask & ((1ull << carg) - 1ull)) : 0;

        if (lane < mr && ((rowmask >> lane) & 1ull))
            rcomp[(int)__popcll(rowmask & ltm)] = rS[lane];
        if (lane < mc && carg >= 0) {
            int cp = (int)__popcll(colmask & ltm);
            ccomp[cp] = cb;
            cmeta[cp] = make_float2(cmin, __int_as_float(cargc));
        }
        __syncthreads();
        float4 rb = make_float4(0,0,0,0);
        if (lane < mrP) rb = rcomp[lane];
        cb = make_float4(0,0,0,0); cba = 0.f;
        float vj = 0.f; int cargf = 0;
        if (lane < mcP) {
            cb = ccomp[lane];
            cba = (cb.z - cb.x) * (cb.w - cb.y);
            float2 cm2 = cmeta[lane];
            vj = cm2.x; cargf = __float_as_int(cm2.y);
        }

        // ---- greedy init
        unsigned long long rowfree = (mrP >= 64) ? ~0ull : ((1ull << mrP) - 1ull);
        unsigned long long amask = 0ull;
        for (int j = 0; j < mcP; ++j) {
            int ia = rl_i(cargf, j);
            if ((rowfree >> ia) & 1ull) { rowfree &= ~(1ull << ia); amask |= (1ull << j); }
        }
        int   pmrow = 0;
        float urow  = 0.f;
        float4 cm = make_float4(0,0,0,0);
        {
            float gx = __shfl(rb.x, cargf), gy = __shfl(rb.y, cargf);
            float gz = __shfl(rb.z, cargf), gw = __shfl(rb.w, cargf);
            bool gm = (lane < mcP) && ((amask >> lane) & 1ull);
            if (gm) { pmrow = cargf + 1; cm = make_float4(gx, gy, gz, gw); }
        }

        // ---- JV shortest augmenting path for remaining free rows
        for (int r = 1; r <= mrP; ++r) {
            if (!((rowfree >> (r - 1)) & 1ull)) continue;

            const float rtx = rl_f(rb.x, r-1), rty = rl_f(rb.y, r-1);
            const float rtz = rl_f(rb.z, r-1), rtw = rl_f(rb.w, r-1);
            float rx = rtx, ry = rty, rz = rtz, rw = rtw;
            float ra = (rz - rx) * (rw - ry);
            float u0 = 0.f, u_free = 0.f, minvj = INFINITY;
            int   wayj = 0, j0cur = 0, j0n = 0;
            bool  usedj = (lane >= nC);
            bool  found = false;

            for (int guard = 0; guard <= 66; ++guard) {
                float iou = 0.f;
                if (lane < mcP) {
                    float iw = fmaxf(fminf(rz, cb.z) - fmaxf(rx, cb.x), 0.f);
                    float ih = fmaxf(fminf(rw, cb.w) - fmaxf(ry, cb.y), 0.f);
                    float inter = iw * ih;
                    iou = inter / (ra + cba - inter);
                }
                float cur = -iou - u0 - vj;
                if (!usedj && cur < minvj) { minvj = cur; wayj = j0cur; }

                unsigned key = 0xFFFFFFFFu;
                if (!usedj)
                    key = ((__float_as_uint(minvj) | 0x80000000u) & 0xFFFFFF80u)
                          | (pmrow ? 64u : 0u) | (unsigned)lane;
                MIN_DPP_STEP(0xB1)  MIN_DPP_STEP(0x4E)  MIN_DPP_STEP(0x141)
                MIN_DPP_STEP(0x140) MIN_DPP_STEP(0x142) MIN_DPP_STEP(0x143)
                unsigned k63 = (unsigned)rl_i((int)key, 63);
                if (k63 == 0xFFFFFFFFu) break;
                const int   jl    = (int)(k63 & 63u);
                const float delta = rl_f(minvj, jl);

                u_free += delta;
                if (usedj) { vj -= delta; urow += delta; }
                else       { minvj -= delta; }

                if (!(k63 & 64u)) { j0n = jl + 1; found = true; break; }

                if (lane == jl) usedj = true;
                u0 = rl_f(urow, jl);
                rx = rl_f(cm.x, jl); ry = rl_f(cm.y, jl);
                rz = rl_f(cm.z, jl); rw = rl_f(cm.w, jl);
                ra = (rz - rx) * (rw - ry);
                j0cur = jl + 1;
            }

            if (!found) continue;

            {
                int src = (wayj > 0) ? (wayj - 1) : 0;
                int   pp = __shfl(pmrow, src);
                float pu = __shfl(urow,  src);
                float p0 = __shfl(cm.x, src), p1 = __shfl(cm.y, src);
                float p2 = __shfl(cm.z, src), p3 = __shfl(cm.w, src);
                bool fromRoot = (wayj == 0);
                int   np = fromRoot ? r      : pp;
                float nu = fromRoot ? u_free : pu;
                float n0 = fromRoot ? rtx : p0, n1 = fromRoot ? rty : p1;
                float n2 = fromRoot ? rtz : p2, n3 = fromRoot ? rtw : p3;
                int jj = j0n;
                for (int hop = 0; hop < 66 && jj != 0; ++hop) {
                    int j1 = rl_i(wayj, jj - 1);
                    if (lane == jj - 1) {
                        pmrow = np; urow = nu;
                        cm = make_float4(n0, n1, n2, n3);
                    }
                    jj = j1;
                }
            }
        }

        // ---- matched IoU sum via DPP add tree
        float acc = 0.f;
        if (lane < mcP && pmrow != 0) {
            float iw = fmaxf(fminf(cm.z, cb.z) - fmaxf(cm.x, cb.x), 0.f);
            float ih = fmaxf(fminf(cm.w, cb.w) - fmaxf(cm.y, cb.y), 0.f);
            float inter = iw * ih;
            float cmA = (cm.z - cm.x) * (cm.w - cm.y);
            acc = inter / (cmA + cba - inter);
        }
        SUM_DPP_STEP(0xB1)  SUM_DPP_STEP(0x4E)  SUM_DPP_STEP(0x141)
        SUM_DPP_STEP(0x140) SUM_DPP_STEP(0x142) SUM_DPP_STEP(0x143)
        blockContrib = rl_f(acc, 63);
    } while (0);

    // ---- tail: publish partials; workers release flag, block 0 finalizes
    if (lane == 0) {
        sum_part[blk] = blockContrib;
        m1_part[blk]  = m1;
        m2_part[blk]  = m2;
    }
    if (blk != 0) {
        if (lane == 0)
            __hip_atomic_store(&flags[blk], 1, __ATOMIC_RELEASE, __HIP_MEMORY_SCOPE_AGENT);
        return;
    }

    if (lane >= 1 && lane < NBLK) {
        while (__hip_atomic_load(&flags[lane], __ATOMIC_ACQUIRE,
                                 __HIP_MEMORY_SCOPE_AGENT) != 1)
            __builtin_amdgcn_s_sleep(1);
    }
    float s = 0.f; int a1 = 0, a2 = 0;
    if (lane < NBLK) { s = sum_part[lane]; a1 = m1_part[lane]; a2 = m2_part[lane]; }
    float st = s; int t1 = a1, t2 = a2;
    #pragma unroll
    for (int k = 1; k < NCLS; ++k) {
        st += __shfl(s, lane + k);
        t1 += __shfl(a1, lane + k);
        t2 += __shfl(a2, lane + k);
    }
    float per;
    {
        float denom = fmaxf(fmaxf((float)t1, (float)t2), 1.f);
        float pv = 1.f - st / denom;
        bool bz = (t1 == 0) && (t2 == 0);
        bool oz = ((t1 == 0) != (t2 == 0));
        per = bz ? 0.f : (oz ? 1.f : pv);
    }
    float accm = 0.f;
    #pragma unroll
    for (int bb = 0; bb < BIMG; ++bb) accm += __shfl(per, bb * NCLS);
    if (lane == 0) out[0] = accm / (float)BIMG;
}

extern "C" void kernel_launch(void* const* d_in, const int* in_sizes, int n_in,
                              void* d_out, int out_size, void* d_ws, size_t ws_size,
                              hipStream_t stream) {
    const float* b1 = (const float*)d_in[0];
    const float* b2 = (const float*)d_in[1];

    // Diagnostic: NREP serialized generations, each in its own ws slice
    // (flags re-poisoned to 0xAA before every timed call -> fresh per launch).
    for (int g = 0; g < NREP; ++g) {
        float* sum_part = (float*)d_ws + (size_t)g * GEN_STRIDE;  // [40] f32
        int*   m1_part  = (int*)(sum_part + NBLK);                // [40] i32
        int*   m2_part  = m1_part + NBLK;                         // [40] i32
        int*   flags    = m2_part + NBLK;                         // [40] i32
        det_fused_kernel<<<NBLK, 64, 0, stream>>>(b1, b2, sum_part, m1_part,
                                                  m2_part, flags, (float*)d_out);
    }
}

// Round 8
// 65.561 us; speedup vs baseline: 5.8546x; 5.8546x over previous
//
#include <hip/hip_runtime.h>
#include <math.h>

// DetectionLoss: masked pairwise IoU + exact Hungarian + scalar loss.
//
// r8: r4 skeleton (best measured fused variant, exec ~25us) + two surgical
// cycle cuts, sized for the low-clock regime (tiny latency-bound kernel runs
// at ~0.6 GHz; 600 cycles ~= 1us):
//   - NO compaction round-trip / reorientation: JV runs on original lane
//     indexing with ALL 64 lanes as columns. Non-colmask columns are
//     zero-cost to every kept row (overlap is symmetric), and adding
//     zero-cost columns never changes the optimal sum -> exact.
//   - single-u32 DPP argmin (~110cy) instead of the 18-bpermute shfl tree
//     (~800cy/iter); reduced costs are >= 0 in JV so the |0x80000000
//     monotone key is valid; 25-bit truncation perturbs sum <= ~1e-6.
//   - keep r4's __shfl box broadcasts + pre-pull augment (r5's readlane
//     rewrite of those coincided with a +5us regression).

constexpr int BIMG = 8;
constexpr int NBOX = 200;
constexpr int NCLS = 5;
constexpr int NBLK = BIMG * NCLS;
constexpr float SCORE_THR = 0.001f;

__device__ __forceinline__ int   rl_i(int x, int l)   { return __builtin_amdgcn_readlane(x, l); }
__device__ __forceinline__ float rl_f(float x, int l) { return __int_as_float(__builtin_amdgcn_readlane(__float_as_int(x), l)); }

#define MIN_DPP_STEP(CTRL)                                                   \
    {                                                                        \
        unsigned ok = (unsigned)__builtin_amdgcn_update_dpp(                 \
            (int)key, (int)key, (CTRL), 0xF, 0xF, false);                    \
        key = (ok < key) ? ok : key;                                         \
    }
#define SUM_DPP_STEP(CTRL)                                                   \
    {                                                                        \
        float o = __int_as_float(__builtin_amdgcn_update_dpp(                \
            __float_as_int(acc), __float_as_int(acc), (CTRL), 0xF, 0xF, false)); \
        acc += o;                                                            \
    }

__global__ void __launch_bounds__(64)
det_fused_kernel(const float* __restrict__ boxes1,
                 const float* __restrict__ boxes2,
                 float* __restrict__ sum_part,
                 int* __restrict__ m1_part, int* __restrict__ m2_part,
                 int* __restrict__ flags,
                 float* __restrict__ out)
{
    const int lane = threadIdx.x;
    const int blk  = blockIdx.x;
    const int b    = blk / NCLS;
    const int ci   = blk % NCLS;
    const int cls  = (ci == 0) ? 1 : (ci == 1) ? 2 : (ci == 2) ? 3 : (ci == 3) ? 5 : 7;
    const unsigned long long ltm = (1ull << lane) - 1ull;

    __shared__ float4 bs1[NBOX], bs2[NBOX];      // class-compacted boxes
    // fallback-only JV state (n > 64; practically unreachable)
    __shared__ float uarr[NBOX + 1], varr[NBOX + 1], minvarr[NBOX + 1];
    __shared__ int   wayarr[NBOX + 1], parr[NBOX + 1], usedarr[NBOX + 1];

    const float* g1 = boxes1 + (size_t)b * NBOX * 6;
    const float* g2 = boxes2 + (size_t)b * NBOX * 6;

    // ---- phase 1: hoist ALL global loads (parallel miss latency), compact
    float2 A[12], B[12];
    #pragma unroll
    for (int c = 0; c < 4; ++c) {
        int t = c * 64 + lane;
        if (t < NBOX) {
            const float2* p = (const float2*)(g1 + (size_t)t * 6);
            A[3*c] = p[0]; A[3*c+1] = p[1]; A[3*c+2] = p[2];
            const float2* q = (const float2*)(g2 + (size_t)t * 6);
            B[3*c] = q[0]; B[3*c+1] = q[1]; B[3*c+2] = q[2];
        } else {
            A[3*c] = A[3*c+1] = make_float2(0.f, 0.f); A[3*c+2] = make_float2(0.f, -1.f);
            B[3*c] = B[3*c+1] = make_float2(0.f, 0.f); B[3*c+2] = make_float2(0.f, -1.f);
        }
    }
    int m1 = 0, m2 = 0;
    #pragma unroll
    for (int c = 0; c < 4; ++c) {
        int t = c * 64 + lane;
        bool pr = (t < NBOX) && (A[3*c+2].x > SCORE_THR) && ((int)A[3*c+2].y == cls);
        unsigned long long mk = __ballot(pr);
        if (pr) bs1[m1 + (int)__popcll(mk & ltm)] =
            make_float4(A[3*c].x, A[3*c].y, A[3*c+1].x, A[3*c+1].y);
        m1 += (int)__popcll(mk);
        pr = (t < NBOX) && (B[3*c+2].x > SCORE_THR) && ((int)B[3*c+2].y == cls);
        mk = __ballot(pr);
        if (pr) bs2[m2 + (int)__popcll(mk & ltm)] =
            make_float4(B[3*c].x, B[3*c].y, B[3*c+1].x, B[3*c+1].y);
        m2 += (int)__popcll(mk);
    }
    __syncthreads();

    float blockContrib = 0.f;

    do {
        if (m1 == 0 || m2 == 0) break;
        const int nmax = (m1 > m2) ? m1 : m2;

        if (nmax > 64) {
            // =================== LDS fallback (n > 64) ====================
            const int n = nmax;
            for (int j = lane; j <= n; j += 64) { varr[j] = 0.f; parr[j] = 0; uarr[j] = 0.f; }
            __syncthreads();
            int j0 = 0;
            for (int i2 = 1; i2 <= n; ++i2) {
                if (lane == 0) parr[0] = i2;
                for (int j = lane; j <= n; j += 64) { minvarr[j] = INFINITY; usedarr[j] = 0; }
                j0 = 0;
                __syncthreads();
                for (int it = 0; it <= n + 1; ++it) {
                    if (lane == 0) usedarr[j0] = 1;
                    __syncthreads();
                    const int i0 = parr[j0];
                    const float u0 = uarr[i0];
                    const bool rowReal = (i0 <= m1);
                    float4 rbx = make_float4(0,0,0,0); float ra = 0.f;
                    if (rowReal) { rbx = bs1[i0-1]; ra = (rbx.z-rbx.x)*(rbx.w-rbx.y); }
                    for (int j = lane; j <= n; j += 64) {
                        if (j >= 1 && !usedarr[j]) {
                            float cost = 0.f;
                            if (rowReal && j <= m2) {
                                float4 cbx = bs2[j-1];
                                float iw = fmaxf(fminf(rbx.z, cbx.z) - fmaxf(rbx.x, cbx.x), 0.f);
                                float ih = fmaxf(fminf(rbx.w, cbx.w) - fmaxf(rbx.y, cbx.y), 0.f);
                                float inter = iw * ih;
                                float ca = (cbx.z-cbx.x)*(cbx.w-cbx.y);
                                cost = -(inter / (ra + ca - inter));
                            }
                            float curv = cost - u0 - varr[j];
                            if (curv < minvarr[j]) { minvarr[j] = curv; wayarr[j] = j0; }
                        }
                    }
                    __syncthreads();
                    float bv = INFINITY; int bu = 0, bj = n + 1;
                    for (int j = lane; j <= n; j += 64) {
                        float m = usedarr[j] ? INFINITY : minvarr[j];
                        int un = (parr[j] == 0) ? 1 : 0;
                        if (m < bv || (m == bv && (un > bu || (un == bu && j < bj))))
                            { bv = m; bu = un; bj = j; }
                    }
                    #pragma unroll
                    for (int off = 32; off; off >>= 1) {
                        float ov2 = __shfl_xor(bv, off);
                        int ou = __shfl_xor(bu, off);
                        int oj = __shfl_xor(bj, off);
                        if (ov2 < bv || (ov2 == bv && (ou > bu || (ou == bu && oj < bj))))
                            { bv = ov2; bu = ou; bj = oj; }
                    }
                    j0 = bj;
                    const float delta = bv;
                    for (int j = lane; j <= n; j += 64) {
                        if (usedarr[j]) { uarr[parr[j]] += delta; varr[j] -= delta; }
                        else            { minvarr[j] -= delta; }
                    }
                    __syncthreads();
                    if (parr[j0] == 0) break;
                }
                if (lane == 0) {
                    int jj = j0, gg = 0;
                    while (jj != 0 && gg++ <= n + 1) { int j1 = wayarr[jj]; parr[jj] = parr[j1]; jj = j1; }
                }
                __syncthreads();
            }
            float contrib = 0.f;
            for (int j = lane; j <= n; j += 64) {
                if (j >= 1 && j <= m2) {
                    int pi = parr[j];
                    if (pi >= 1 && pi <= m1) {
                        float4 rbx = bs1[pi-1], cbx = bs2[j-1];
                        float iw = fmaxf(fminf(rbx.z, cbx.z) - fmaxf(rbx.x, cbx.x), 0.f);
                        float ih = fmaxf(fminf(rbx.w, cbx.w) - fmaxf(rbx.y, cbx.y), 0.f);
                        float inter = iw * ih;
                        float ra = (rbx.z-rbx.x)*(rbx.w-rbx.y);
                        float ca = (cbx.z-cbx.x)*(cbx.w-cbx.y);
                        contrib += inter / (ra + ca - inter);
                    }
                }
            }
            #pragma unroll
            for (int off = 32; off; off >>= 1) contrib += __shfl_xor(contrib, off);
            blockContrib = contrib;
            break;
        }

        // ====================== register fast path ========================
        const bool sw = (m1 > m2);           // rows = smaller side
        const float4* rS = sw ? bs2 : bs1;
        const float4* cS = sw ? bs1 : bs2;
        const int mr = sw ? m2 : m1;
        const int mc = sw ? m1 : m2;

        float4 cb = make_float4(0,0,0,0);
        if (lane < mc) cb = cS[lane];
        const float cba = (cb.z - cb.x) * (cb.w - cb.y);
        float4 rb = make_float4(0,0,0,0);
        if (lane < mr) rb = rS[lane];

        // ---- merged NZ scan + column reduction, ORIGINAL indexing, x4 unroll
        unsigned long long rowmask = 0ull;
        float cmin = 0.f; int carg = -1;
        #define SCAN1(ii)                                                      \
        {                                                                      \
            float4 rbv = rS[(ii)];                                             \
            float iw = fminf(rbv.z, cb.z) - fmaxf(rbv.x, cb.x);                \
            float ih = fminf(rbv.w, cb.w) - fmaxf(rbv.y, cb.y);                \
            bool ov = (lane < mc) && (iw > 0.f) && (ih > 0.f);                 \
            unsigned long long bal = __ballot(ov);                             \
            if (bal) rowmask |= (1ull << (ii));                                \
            if (ov) {                                                          \
                float inter = iw * ih;                                         \
                float ra2 = (rbv.z - rbv.x) * (rbv.w - rbv.y);                 \
                float cst = -(inter / (ra2 + cba - inter));                    \
                if (cst < cmin) { cmin = cst; carg = (ii); }                   \
            }                                                                  \
        }
        int i = 0;
        for (; i + 4 <= mr; i += 4) { SCAN1(i) SCAN1(i+1) SCAN1(i+2) SCAN1(i+3) }
        for (; i < mr; ++i) { SCAN1(i) }
        #undef SCAN1

        if (rowmask == 0ull) break;
        const unsigned long long colmask = __ballot(carg >= 0);

        // duals: v[j] = column reduction for NZ cols, 0 for zero-cost cols
        float vj = (carg >= 0) ? cmin : 0.f;

        // ---- greedy init over NZ columns (scalar ctz loop, ~4 iters)
        unsigned long long rowfree = rowmask;      // kept rows, original idx
        unsigned long long amask = 0ull;
        {
            unsigned long long cmk = colmask;
            while (cmk) {
                int j = (int)__builtin_ctzll(cmk); cmk &= cmk - 1ull;
                int ia = rl_i(carg, j);
                if ((rowfree >> ia) & 1ull) { rowfree &= ~(1ull << ia); amask |= (1ull << j); }
            }
        }
        int    pmrow = 0;                 // matched row (original idx +1)
        float  urow  = 0.f;
        float4 cm = make_float4(0,0,0,0); // matched row's box
        {
            int ci2 = (carg >= 0) ? carg : 0;
            float gx = __shfl(rb.x, ci2), gy = __shfl(rb.y, ci2);
            float gz = __shfl(rb.z, ci2), gw = __shfl(rb.w, ci2);
            bool gm = (amask >> lane) & 1ull;
            if (gm) { pmrow = carg + 1; cm = make_float4(gx, gy, gz, gw); }
        }

        // ---- JV shortest augmenting path for remaining free kept rows.
        // ALL 64 lanes are columns (zero-cost ones included) -> exact.
        unsigned long long rrem = rowfree;
        while (rrem) {
            const int r0 = (int)__builtin_ctzll(rrem);
            rrem &= rrem - 1ull;

            const float rtx = rl_f(rb.x, r0), rty = rl_f(rb.y, r0);
            const float rtz = rl_f(rb.z, r0), rtw = rl_f(rb.w, r0);
            float rx = rtx, ry = rty, rz = rtz, rw = rtw;
            float ra = (rz - rx) * (rw - ry);
            float u0 = 0.f, u_free = 0.f, minvj = INFINITY;
            int   wayj = 0, j0cur = 0, j0n = 0;
            bool  usedj = false, found = false;

            for (int guard = 0; guard <= 70; ++guard) {
                float iw = fmaxf(fminf(rz, cb.z) - fmaxf(rx, cb.x), 0.f);
                float ih = fmaxf(fminf(rw, cb.w) - fmaxf(ry, cb.y), 0.f);
                float inter = iw * ih;
                float iou = inter / (ra + cba - inter);   // dummy lanes: 0/ra = 0
                float cur = -iou - u0 - vj;
                if (!usedj && cur < minvj) { minvj = cur; wayj = j0cur; }

                // packed argmin: [31:7] trunc monotone key (minv >= 0 in JV),
                // bit6 = matched (prefer unmatched on ties), [5:0] lane.
                unsigned key = usedj ? 0xFFFFFFFFu
                    : (((__float_as_uint(minvj) | 0x80000000u) & 0xFFFFFF80u)
                       | (pmrow ? 64u : 0u) | (unsigned)lane);
                MIN_DPP_STEP(0xB1)  MIN_DPP_STEP(0x4E)  MIN_DPP_STEP(0x141)
                MIN_DPP_STEP(0x140) MIN_DPP_STEP(0x142) MIN_DPP_STEP(0x143)
                unsigned k63 = (unsigned)rl_i((int)key, 63);
                if (k63 == 0xFFFFFFFFu) break;            // defensive
                const int   jl    = (int)(k63 & 63u);
                const float delta = rl_f(minvj, jl);      // exact min value

                u_free += delta;
                if (usedj) { vj -= delta; if (pmrow) urow += delta; }
                else       { minvj -= delta; }

                if (!(k63 & 64u)) { j0n = jl + 1; found = true; break; }

                if (lane == jl) usedj = true;
                u0 = rl_f(urow, jl);
                rx = rl_f(cm.x, jl); ry = rl_f(cm.y, jl);
                rz = rl_f(cm.z, jl); rw = rl_f(cm.w, jl);
                ra = (rz - rx) * (rw - ry);
                j0cur = jl + 1;
            }

            if (!found) continue;  // defensive

            // ---- augment: pre-pull payload from way-source, uniform chase
            {
                int src = (wayj > 0) ? (wayj - 1) : 0;
                int   pp = __shfl(pmrow, src);
                float pu = __shfl(urow,  src);
                float p0 = __shfl(cm.x, src), p1 = __shfl(cm.y, src);
                float p2 = __shfl(cm.z, src), p3 = __shfl(cm.w, src);
                bool fromRoot = (wayj == 0);
                int   np = fromRoot ? (r0 + 1) : pp;
                float nu = fromRoot ? u_free : pu;
                float n0 = fromRoot ? rtx : p0, n1 = fromRoot ? rty : p1;
                float n2 = fromRoot ? rtz : p2, n3 = fromRoot ? rtw : p3;
                int jj = j0n;
                for (int hop = 0; hop < 70 && jj != 0; ++hop) {
                    int j1 = rl_i(wayj, jj - 1);
                    if (lane == jj - 1) {
                        pmrow = np; urow = nu;
                        cm = make_float4(n0, n1, n2, n3);
                    }
                    jj = j1;
                }
            }
        }

        // ---- matched IoU sum via DPP add tree (real columns only)
        float acc = 0.f;
        if (lane < mc && pmrow != 0) {
            float iw = fmaxf(fminf(cm.z, cb.z) - fmaxf(cm.x, cb.x), 0.f);
            float ih = fmaxf(fminf(cm.w, cb.w) - fmaxf(cm.y, cb.y), 0.f);
            float inter = iw * ih;
            float cmA = (cm.z - cm.x) * (cm.w - cm.y);
            acc = inter / (cmA + cba - inter);
        }
        SUM_DPP_STEP(0xB1)  SUM_DPP_STEP(0x4E)  SUM_DPP_STEP(0x141)
        SUM_DPP_STEP(0x140) SUM_DPP_STEP(0x142) SUM_DPP_STEP(0x143)
        blockContrib = rl_f(acc, 63);
    } while (0);

    // ---- tail: publish partials; workers release flag, block 0 finalizes
    if (lane == 0) {
        sum_part[blk] = blockContrib;
        m1_part[blk]  = m1;
        m2_part[blk]  = m2;
    }
    if (blk != 0) {
        if (lane == 0)
            __hip_atomic_store(&flags[blk], 1, __ATOMIC_RELEASE, __HIP_MEMORY_SCOPE_AGENT);
        return;
    }

    if (lane >= 1 && lane < NBLK) {
        while (__hip_atomic_load(&flags[lane], __ATOMIC_ACQUIRE,
                                 __HIP_MEMORY_SCOPE_AGENT) != 1)
            __builtin_amdgcn_s_sleep(1);
    }
    float s = 0.f; int a1 = 0, a2 = 0;
    if (lane < NBLK) { s = sum_part[lane]; a1 = m1_part[lane]; a2 = m2_part[lane]; }
    float st = s; int t1 = a1, t2 = a2;
    #pragma unroll
    for (int k = 1; k < NCLS; ++k) {
        st += __shfl(s, lane + k);
        t1 += __shfl(a1, lane + k);
        t2 += __shfl(a2, lane + k);
    }
    float per;
    {
        float denom = fmaxf(fmaxf((float)t1, (float)t2), 1.f);
        float pv = 1.f - st / denom;
        bool bz = (t1 == 0) && (t2 == 0);
        bool oz = ((t1 == 0) != (t2 == 0));
        per = bz ? 0.f : (oz ? 1.f : pv);
    }
    float accm = 0.f;
    #pragma unroll
    for (int bb = 0; bb < BIMG; ++bb) accm += __shfl(per, bb * NCLS);
    if (lane == 0) out[0] = accm / (float)BIMG;
}

extern "C" void kernel_launch(void* const* d_in, const int* in_sizes, int n_in,
                              void* d_out, int out_size, void* d_ws, size_t ws_size,
                              hipStream_t stream) {
    const float* b1 = (const float*)d_in[0];
    const float* b2 = (const float*)d_in[1];
    float* sum_part = (float*)d_ws;                 // [40] f32
    int*   m1_part  = (int*)(sum_part + NBLK);      // [40] i32
    int*   m2_part  = m1_part + NBLK;               // [40] i32
    int*   flags    = m2_part + NBLK;               // [40] i32 (poisoned != 1)

    det_fused_kernel<<<NBLK, 64, 0, stream>>>(b1, b2, sum_part, m1_part, m2_part,
                                              flags, (float*)d_out);
}